// Round 5
// baseline (148.056 us; speedup 1.0000x reference)
//
#include <hip/hip_runtime.h>
#include <hip/hip_cooperative_groups.h>
#include <math.h>

namespace cg = cooperative_groups;

#define CBLK 512   // 2 blocks/CU on 256 CUs -> guaranteed co-resident at VGPR<=256
#define NTHR 256
#define REGN 44    // f32x4 held per thread = 176 data VGPRs (88 MB chip-wide)

#define NBLK 2048  // fallback grid

typedef float f32x4 __attribute__((ext_vector_type(4)));

// Combine two online-softmax partials (m1,s1) <- (m1,s1) ⊕ (m2,s2)
__device__ __forceinline__ void ms_combine(float& m, float& s, float m2, float s2) {
    float mn = fmaxf(m, m2);
    s = s * __expf(m - mn) + s2 * __expf(m2 - mn);
    m = mn;
}

// Block-level (m,s) reduce; result broadcast to all threads via LDS.
__device__ __forceinline__ void block_reduce_broadcast(float& m, float& s) {
    #pragma unroll
    for (int off = 32; off > 0; off >>= 1) {
        float m2 = __shfl_down(m, off);
        float s2 = __shfl_down(s, off);
        ms_combine(m, s, m2, s2);
    }
    __shared__ float sm[NTHR / 64], ss[NTHR / 64], g[2];
    int wid = threadIdx.x >> 6;
    if ((threadIdx.x & 63) == 0) { sm[wid] = m; ss[wid] = s; }
    __syncthreads();
    if (threadIdx.x == 0) {
        m = sm[0]; s = ss[0];
        #pragma unroll
        for (int w = 1; w < NTHR / 64; ++w) ms_combine(m, s, sm[w], ss[w]);
        g[0] = m; g[1] = s;
    }
    __syncthreads();
    m = g[0]; s = g[1];
    __syncthreads();   // protect LDS reuse across calls
}

// ---- single-pass cooperative kernel: 88 MB of x register-resident ----------
__global__ __launch_bounds__(NTHR, 2) void softmax_coop(
        const float* __restrict__ x, float* __restrict__ out,
        float* __restrict__ ws, long n4) {
    const f32x4* __restrict__ x4 = (const f32x4*)x;
    f32x4* __restrict__ o4 = (f32x4*)out;
    const long T = (long)CBLK * NTHR;                  // total threads
    const long t = (long)blockIdx.x * NTHR + threadIdx.x;

    // Register-resident region: first REGN*T f32x4, static indexing.
    f32x4 v[REGN];
    #pragma unroll
    for (int j = 0; j < REGN; ++j) v[j] = x4[t + (long)j * T];

    float m = -INFINITY;
    #pragma unroll
    for (int j = 0; j < REGN; ++j)
        m = fmaxf(m, fmaxf(fmaxf(v[j].x, v[j].y), fmaxf(v[j].z, v[j].w)));

    // Tail region: online (mt, st), streamed.
    float mt = -INFINITY, st = 0.0f;
    for (long i = (long)REGN * T + t; i < n4; i += T) {
        f32x4 w = x4[i];
        float vm = fmaxf(fmaxf(w.x, w.y), fmaxf(w.z, w.w));
        if (vm > mt) { st *= __expf(mt - vm); mt = vm; }  // first iter: st stays 0
        st += __expf(w.x - mt) + __expf(w.y - mt)
            + __expf(w.z - mt) + __expf(w.w - mt);
    }

    float mf = fmaxf(m, mt);
    float s = 0.0f;
    #pragma unroll
    for (int j = 0; j < REGN; ++j)
        s += __expf(v[j].x - mf) + __expf(v[j].y - mf)
           + __expf(v[j].z - mf) + __expf(v[j].w - mf);
    s += st * __expf(mt - mf);   // exp(-inf)=0 covers empty tail

    block_reduce_broadcast(mf, s);
    if (threadIdx.x == 0) {
        ws[blockIdx.x]        = mf;
        ws[CBLK + blockIdx.x] = s;
    }
    __threadfence();
    cg::this_grid().sync();

    // Redundant per-block combine of CBLK partials (deterministic, 4 KB read).
    float gm = -INFINITY, gs = 0.0f;
    for (int i = threadIdx.x; i < CBLK; i += NTHR)
        ms_combine(gm, gs, ws[i], ws[CBLK + i]);
    block_reduce_broadcast(gm, gs);
    const float ginv = 1.0f / gs;

    // Write register-resident region straight from regs (NT stores).
    #pragma unroll
    for (int j = 0; j < REGN; ++j) {
        f32x4 o;
        o.x = __expf(v[j].x - gm) * ginv;
        o.y = __expf(v[j].y - gm) * ginv;
        o.z = __expf(v[j].z - gm) * ginv;
        o.w = __expf(v[j].w - gm) * ginv;
        __builtin_nontemporal_store(o, &o4[t + (long)j * T]);
    }
    // Tail: re-read (recently touched -> likely L3-resident).
    for (long i = (long)REGN * T + t; i < n4; i += T) {
        f32x4 w = x4[i];
        f32x4 o;
        o.x = __expf(w.x - gm) * ginv;
        o.y = __expf(w.y - gm) * ginv;
        o.z = __expf(w.z - gm) * ginv;
        o.w = __expf(w.w - gm) * ginv;
        __builtin_nontemporal_store(o, &o4[i]);
    }
}

// ---------------- fallback two-pass path (any size / coop failure) ----------
__global__ __launch_bounds__(NTHR) void softmax_partials(
        const float* __restrict__ x, long n4, float* __restrict__ ws) {
    const f32x4* __restrict__ x4 = (const f32x4*)x;
    long tid    = (long)blockIdx.x * blockDim.x + threadIdx.x;
    long stride = (long)gridDim.x * blockDim.x;
    float m = -INFINITY, s = 0.0f;
    for (long i = tid; i < n4; i += stride) {
        f32x4 v = x4[i];
        float vm = fmaxf(fmaxf(v.x, v.y), fmaxf(v.z, v.w));
        if (vm > m) { s *= __expf(m - vm); m = vm; }
        s += __expf(v.x - m) + __expf(v.y - m)
           + __expf(v.z - m) + __expf(v.w - m);
    }
    block_reduce_broadcast(m, s);
    if (threadIdx.x == 0) {
        ws[blockIdx.x]             = m;
        ws[gridDim.x + blockIdx.x] = s;
    }
}

__global__ __launch_bounds__(NTHR) void softmax_write(
        const float* __restrict__ x, float* __restrict__ out, long n4,
        const float* __restrict__ ws, int nparts) {
    float m = -INFINITY, s = 0.0f;
    for (int i = threadIdx.x; i < nparts; i += NTHR)
        ms_combine(m, s, ws[i], ws[nparts + i]);
    block_reduce_broadcast(m, s);
    const float gm = m, ginv = 1.0f / s;

    const f32x4* __restrict__ x4 = (const f32x4*)x;
    f32x4* __restrict__ o4 = (f32x4*)out;
    long tid    = (long)blockIdx.x * blockDim.x + threadIdx.x;
    long stride = (long)gridDim.x * blockDim.x;
    for (long i = tid; i < n4; i += stride) {
        f32x4 v = x4[i];
        f32x4 o;
        o.x = __expf(v.x - gm) * ginv;
        o.y = __expf(v.y - gm) * ginv;
        o.z = __expf(v.z - gm) * ginv;
        o.w = __expf(v.w - gm) * ginv;
        __builtin_nontemporal_store(o, &o4[i]);
    }
}

extern "C" void kernel_launch(void* const* d_in, const int* in_sizes, int n_in,
                              void* d_out, int out_size, void* d_ws, size_t ws_size,
                              hipStream_t stream) {
    const float* x = (const float*)d_in[0];
    float* out     = (float*)d_out;
    float* ws      = (float*)d_ws;
    long n  = (long)in_sizes[0];
    long n4 = n >> 2;

    bool coop_ok = false;
    if ((n & 3) == 0 && n4 >= (long)REGN * CBLK * NTHR) {
        void* args[] = { (void*)&x, (void*)&out, (void*)&ws, (void*)&n4 };
        hipError_t e = hipLaunchCooperativeKernel((const void*)softmax_coop,
                                                  dim3(CBLK), dim3(NTHR),
                                                  args, 0, stream);
        coop_ok = (e == hipSuccess);
    }
    if (!coop_ok) {
        softmax_partials<<<NBLK, NTHR, 0, stream>>>(x, n4, ws);
        softmax_write<<<NBLK, NTHR, 0, stream>>>(x, out, n4, ws, NBLK);
    }
}